// Round 5
// baseline (479.331 us; speedup 1.0000x reference)
//
#include <hip/hip_runtime.h>
#include <stdint.h>

// B=2, SQ=SK=2048, HIDDEN=2048, HEADS=16, HEAD_DIM=128.
// DTYPE MODEL (verified): inputs fp32, mask int32, OUTPUT fp32. Internal bf16 MFMA.
// Round 13: QKV/proj GEMMs unchanged (round-12, verified; cross-container clock
// variance explains 146 vs 193 us, not structure). Attention restructured to
// 64-keys-per-barrier: quad-buffered K and V tiles (4x8 KB each, LDS 75 KB,
// still 2 blocks/CU), halving the per-block __syncthreads count 64 -> 32 and
// doubling the work per serial chain. Inner phase code verbatim from the
// verified 32-key body.

#define LOG2E 1.44269504088896340736f
#define INV2PI 0.15915494309189535f

typedef __attribute__((ext_vector_type(8))) short bf16x8;
typedef __attribute__((ext_vector_type(8))) uint16_t u16x8;
typedef __attribute__((ext_vector_type(4))) uint16_t u16x4;
typedef __attribute__((ext_vector_type(4))) float f32x4;

__device__ __forceinline__ uint16_t f2bf(float f) {
  union { float f; uint32_t i; } v; v.f = f;
  uint32_t x = v.i;
  return (uint16_t)((x + 0x7fffu + ((x >> 16) & 1u)) >> 16);  // RTN-even
}
__device__ __forceinline__ uint32_t f_as_u(float f) { union { float f; uint32_t u; } v; v.f = f; return v.u; }
__device__ __forceinline__ float u_as_f(uint32_t u) { union { uint32_t u; float f; } v; v.u = u; return v.f; }
__device__ __forceinline__ void glds16(const void* g, void* l) {
  __builtin_amdgcn_global_load_lds((const __attribute__((address_space(1))) void*)g,
                                   (__attribute__((address_space(3))) void*)l, 16, 0, 0);
}

// fp32 -> bf16, 8 elems/thread, exact grid (n % 2048 == 0).
__global__ __launch_bounds__(256) void convert_f32_bf16(const float* __restrict__ in,
                                                        uint16_t* __restrict__ out) {
  const long i = ((long)blockIdx.x * 256 + threadIdx.x) * 8;
  const f32x4 a = *(const f32x4*)(in + i);
  const f32x4 b = *(const f32x4*)(in + i + 4);
  u16x8 o;
#pragma unroll
  for (int j = 0; j < 4; ++j) { o[j] = f2bf(a[j]); o[4 + j] = f2bf(b[j]); }
  *(u16x8*)(out + i) = o;
}

// All four weights -> one contiguous bf16 buffer W4 = [Wq|Wk|Wv|Wo], 4M elems each.
__global__ __launch_bounds__(256) void convert_w4(const float* __restrict__ Wq,
                                                  const float* __restrict__ Wk,
                                                  const float* __restrict__ Wv,
                                                  const float* __restrict__ Wo,
                                                  uint16_t* __restrict__ W4) {
  const int blk = blockIdx.x;        // 8192 blocks, 2048 per section
  const int sec = blk >> 11;
  const long off = ((long)(blk & 2047) * 256 + threadIdx.x) * 8;
  const float* src = (sec == 0) ? Wq : (sec == 1) ? Wk : (sec == 2) ? Wv : Wo;
  const f32x4 a = *(const f32x4*)(src + off);
  const f32x4 b = *(const f32x4*)(src + off + 4);
  u16x8 o;
#pragma unroll
  for (int j = 0; j < 4; ++j) { o[j] = f2bf(a[j]); o[4 + j] = f2bf(b[j]); }
  *(u16x8*)(W4 + (long)sec * 4194304 + off) = o;
}

// mask int -> additive softmax bias float (0 or -inf). 4096 elems.
__global__ __launch_bounds__(256) void mask_bias(const int* __restrict__ m,
                                                 float* __restrict__ bias) {
  const int i = blockIdx.x * 256 + threadIdx.x;
  bias[i] = m[i] ? 0.0f : -__builtin_inff();
}

// c is the section-local column; C has row stride 2048.
__device__ __forceinline__ void epi_rope_store(uint16_t* C, const f32x4& a, int rowbase,
                                               int c, float oscale) {
  const int f = (c >> 1) & 63;
  const float inv = __builtin_amdgcn_exp2f((float)f * (-13.287712379549449f / 64.0f));
  const float sgn = (c & 1) ? 1.0f : -1.0f;
#pragma unroll
  for (int r = 0; r < 4; ++r) {
    const float val = a[r];
    const float partner = __shfl_xor(val, 1);
    const int s = (rowbase + r) & 2047;
    const float rev = __builtin_amdgcn_fractf((float)s * inv * INV2PI);
    const float sn = __builtin_amdgcn_sinf(rev);
    const float cs = __builtin_amdgcn_cosf(rev);
    C[(long)(rowbase + r) * 2048 + c] = f2bf((val * cs + sgn * partner * sn) * oscale);
  }
}

// ---------------------------------------------------------------------------
// QKV mega-GEMM: 256x256 tile, BK=64, 512 threads = 8 waves (2M x 4N).
// Round-10 verified structure: 2 counted-vmcnt syncs per K-tile.
// LDS map: [256 rows][4 slots of 8]; phys slot p at row r holds logical
// k-slot p ^ ((r>>1)&3); staged via pre-swizzled global source (rule 21).
// ---------------------------------------------------------------------------
__global__ __launch_bounds__(512, 2) void gemm256(const uint16_t* __restrict__ A0,
                                                  const uint16_t* __restrict__ A1,
                                                  const uint16_t* __restrict__ W,
                                                  uint16_t* __restrict__ Qb,
                                                  uint16_t* __restrict__ Kb,
                                                  uint16_t* __restrict__ Vtb,
                                                  int M, int N, int K, float oscale) {
  __shared__ __align__(16) uint16_t As[2][2][8192];  // [buf][kk][256*32] = 64 KiB
  __shared__ __align__(16) uint16_t Bs[2][2][8192];  // 64 KiB
  const int tid = threadIdx.x;
  const int lane = tid & 63;
  const int w = tid >> 6;
  const int r16 = lane & 15, quad = lane >> 4;
  const int wm = w >> 2, wn = w & 3;

  // bijective XCD swizzle (nwg % 8 == 0), column-chunked.
  const int nby = M >> 8;
  const int nwg = gridDim.x;
  const int wg = ((int)blockIdx.x & 7) * (nwg >> 3) + ((int)blockIdx.x >> 3);
  const int by = wg % nby, bx = wg / nby;
  const int m0 = by << 8, n0 = bx << 8;

  const uint16_t* A = (n0 >= 2048) ? A1 : A0;

  // staging: wave w owns chunks 2w, 2w+1 (16 rows each) of every half-tile
  const int srow = 2 * w * 16 + (lane >> 2);           // rows srow, srow+16
  const int ssl = (lane & 3) ^ ((srow >> 1) & 3);      // same for srow+16
  const uint16_t* Ag0 = A + (long)(m0 + srow) * K + ssl * 8;
  const uint16_t* Ag1 = Ag0 + (long)16 * K;
  const uint16_t* Bg0 = W + (long)(n0 + srow) * K + ssl * 8;
  const uint16_t* Bg1 = Bg0 + (long)16 * K;
  const int ldso = w << 10;  // element offset of this wave's first 1 KiB chunk

  // fragment read offsets (elements within one [buf][kk] plane)
  const int sw = (r16 >> 1) & 3;
  const int aoff = (wm * 128 + r16) * 32 + ((quad ^ sw) << 3);
  const int boff = (wn * 64 + r16) * 32 + ((quad ^ sw) << 3);

  f32x4 acc[8][4] = {};
  bf16x8 af[4], bfr[4];

#define SCHED0() __builtin_amdgcn_sched_barrier(0)
#define G_STAGE_A(BUF, KK, T) do { \
    glds16(Ag0 + (long)(T) * 64 + (KK) * 32, &As[BUF][KK][ldso]); \
    glds16(Ag1 + (long)(T) * 64 + (KK) * 32, &As[BUF][KK][ldso + 512]); } while (0)
#define G_STAGE_B(BUF, KK, T) do { \
    glds16(Bg0 + (long)(T) * 64 + (KK) * 32, &Bs[BUF][KK][ldso]); \
    glds16(Bg1 + (long)(T) * 64 + (KK) * 32, &Bs[BUF][KK][ldso + 512]); } while (0)
#define LDS_B(BUF, KK) do { _Pragma("unroll") \
    for (int i = 0; i < 4; ++i) bfr[i] = *(const bf16x8*)&Bs[BUF][KK][boff + i * 512]; } while (0)
#define LDS_A(BUF, KK, MH) do { _Pragma("unroll") \
    for (int i = 0; i < 4; ++i) af[i] = *(const bf16x8*)&As[BUF][KK][aoff + ((MH) * 4 + i) * 512]; } while (0)
#define MFMA16(MH) do { __builtin_amdgcn_s_setprio(1); _Pragma("unroll") \
    for (int mi = 0; mi < 4; ++mi) { _Pragma("unroll") \
      for (int nt = 0; nt < 4; ++nt) \
        acc[(MH) * 4 + mi][nt] = __builtin_amdgcn_mfma_f32_16x16x32_bf16(af[mi], bfr[nt], acc[(MH) * 4 + mi][nt], 0, 0, 0); } \
    __builtin_amdgcn_s_setprio(0); } while (0)
#define VMBAR(NN) do { SCHED0(); \
    asm volatile("s_waitcnt vmcnt(" #NN ")" ::: "memory"); \
    __builtin_amdgcn_s_barrier(); \
    SCHED0(); } while (0)
#define TILE_ITER(T, BC, BN) do { \
    G_STAGE_A(BN, 0, (T) + 1); LDS_B(BC, 0); LDS_A(BC, 0, 0); MFMA16(0); \
    G_STAGE_B(BN, 0, (T) + 1); LDS_A(BC, 0, 1); MFMA16(1); \
    VMBAR(4); \
    G_STAGE_A(BN, 1, (T) + 1); LDS_B(BC, 1); LDS_A(BC, 1, 0); MFMA16(0); \
    G_STAGE_B(BN, 1, (T) + 1); LDS_A(BC, 1, 1); MFMA16(1); \
    VMBAR(4); } while (0)

  // prologue: stage tile 0 fully; land k0 halves, keep k1 halves in flight
  G_STAGE_A(0, 0, 0); G_STAGE_B(0, 0, 0); G_STAGE_A(0, 1, 0); G_STAGE_B(0, 1, 0);
  VMBAR(4);

  const int NT = K >> 6;  // 32 (even); tiles 0..NT-1
  int t = 0;
  for (; t + 2 < NT; t += 2) { TILE_ITER(t, 0, 1); TILE_ITER(t + 1, 1, 0); }
  TILE_ITER(t, 0, 1);  // t == NT-2 (even): stages tile NT-1 into buf 1

  // peeled tail tile NT-1 (buf 1): no staging; drain its k1 at mid-tile
  LDS_B(1, 0); LDS_A(1, 0, 0); MFMA16(0);
  LDS_A(1, 0, 1); MFMA16(1);
  VMBAR(0);
  LDS_B(1, 1); LDS_A(1, 1, 0); MFMA16(0);
  LDS_A(1, 1, 1); MFMA16(1);

#undef G_STAGE_A
#undef G_STAGE_B
#undef LDS_A
#undef LDS_B
#undef TILE_ITER

#pragma unroll
  for (int mt = 0; mt < 8; ++mt)
#pragma unroll
    for (int nt = 0; nt < 4; ++nt) {
      const int col = n0 + wn * 64 + nt * 16 + r16;
      const int rowbase = m0 + wm * 128 + mt * 16 + quad * 4;
      if (n0 < 2048) {
        epi_rope_store(Qb, acc[mt][nt], rowbase, col, oscale);       // Q
      } else if (n0 < 4096) {
        epi_rope_store(Kb, acc[mt][nt], rowbase, col - 2048, 1.0f);  // K
      } else {
        const int c = col - 4096;
        const int h = c >> 7, d = c & 127;
        const int b = rowbase >> 11, s = rowbase & 2047;
        u16x4 pk;
#pragma unroll
        for (int r = 0; r < 4; ++r) pk[r] = f2bf(acc[mt][nt][r]);
        *(u16x4*)(Vtb + (long)((b * 16 + h) * 128 + d) * 2048 + s) = pk;
      }
    }
}

// ---------------------------------------------------------------------------
// Final projection: BM=128, BN=256, BK=64, 8 waves (2M x 4N) -> wave 64x64.
// Grid 32x8 = 256 blocks = one full round on 256 CUs.  vmcnt(3) ledger.
// LDS: As 2x2x[128x32]=32K + Bs 2x2x[256x32]=64K = 96 KiB.
// ---------------------------------------------------------------------------
__global__ __launch_bounds__(512, 2) void gemm_proj(const uint16_t* __restrict__ A0,
                                                    const uint16_t* __restrict__ W,
                                                    float* __restrict__ C,
                                                    int M, int N, int K) {
  __shared__ __align__(16) uint16_t As[2][2][4096];  // [buf][kk][128*32] = 32 KiB
  __shared__ __align__(16) uint16_t Bs[2][2][8192];  // [buf][kk][256*32] = 64 KiB
  const int tid = threadIdx.x;
  const int lane = tid & 63;
  const int w = tid >> 6;
  const int r16 = lane & 15, quad = lane >> 4;
  const int wm = w >> 2, wn = w & 3;

  const int nby = M >> 7;  // BM=128
  const int nwg = gridDim.x;
  const int wg = ((int)blockIdx.x & 7) * (nwg >> 3) + ((int)blockIdx.x >> 3);
  const int by = wg % nby, bx = wg / nby;
  const int m0 = by << 7, n0 = bx << 8;

  // staging: wave w owns A chunk w (16 rows) and B chunks 2w, 2w+1
  const int sa_row = 16 * w + (lane >> 2);
  const int sb_row = 32 * w + (lane >> 2);
  const int ssl = (lane & 3) ^ (((lane >> 2) >> 1) & 3);
  const uint16_t* Ag = A0 + (long)(m0 + sa_row) * K + ssl * 8;
  const uint16_t* Bg0 = W + (long)(n0 + sb_row) * K + ssl * 8;
  const uint16_t* Bg1 = Bg0 + (long)16 * K;

  const int sw = (r16 >> 1) & 3;
  const int aoff = (wm * 64 + r16) * 32 + ((quad ^ sw) << 3);
  const int boff = (wn * 64 + r16) * 32 + ((quad ^ sw) << 3);

  f32x4 acc[4][4] = {};
  bf16x8 af[4], bfr[4];

#define PG_STAGE_A(BUF, KK, T) \
    glds16(Ag + (long)(T) * 64 + (KK) * 32, &As[BUF][KK][w * 512])
#define PG_STAGE_B(BUF, KK, T) do { \
    glds16(Bg0 + (long)(T) * 64 + (KK) * 32, &Bs[BUF][KK][2 * w * 512]); \
    glds16(Bg1 + (long)(T) * 64 + (KK) * 32, &Bs[BUF][KK][2 * w * 512 + 512]); } while (0)
#define PLDS_B(BUF, KK) do { _Pragma("unroll") \
    for (int i = 0; i < 4; ++i) bfr[i] = *(const bf16x8*)&Bs[BUF][KK][boff + i * 512]; } while (0)
#define PLDS_A(BUF, KK) do { _Pragma("unroll") \
    for (int i = 0; i < 4; ++i) af[i] = *(const bf16x8*)&As[BUF][KK][aoff + i * 512]; } while (0)
#define PMFMA(MT0, MT1) do { __builtin_amdgcn_s_setprio(1); _Pragma("unroll") \
    for (int mi = (MT0); mi < (MT1); ++mi) { _Pragma("unroll") \
      for (int nt = 0; nt < 4; ++nt) \
        acc[mi][nt] = __builtin_amdgcn_mfma_f32_16x16x32_bf16(af[mi], bfr[nt], acc[mi][nt], 0, 0, 0); } \
    __builtin_amdgcn_s_setprio(0); } while (0)
#define PTILE(T, BC, BN) do { \
    PG_STAGE_A(BN, 0, (T) + 1); PLDS_B(BC, 0); PLDS_A(BC, 0); PMFMA(0, 2); \
    PG_STAGE_B(BN, 0, (T) + 1); PMFMA(2, 4); \
    VMBAR(3); \
    PG_STAGE_A(BN, 1, (T) + 1); PLDS_B(BC, 1); PLDS_A(BC, 1); PMFMA(0, 2); \
    PG_STAGE_B(BN, 1, (T) + 1); PMFMA(2, 4); \
    VMBAR(3); } while (0)

  PG_STAGE_A(0, 0, 0); PG_STAGE_B(0, 0, 0); PG_STAGE_A(0, 1, 0); PG_STAGE_B(0, 1, 0);
  VMBAR(3);

  const int NT = K >> 6;  // 32
  int t = 0;
  for (; t + 2 < NT; t += 2) { PTILE(t, 0, 1); PTILE(t + 1, 1, 0); }
  PTILE(t, 0, 1);

  PLDS_B(1, 0); PLDS_A(1, 0); PMFMA(0, 4);
  VMBAR(0);
  PLDS_B(1, 1); PLDS_A(1, 1); PMFMA(0, 4);

#undef PG_STAGE_A
#undef PG_STAGE_B
#undef PLDS_A
#undef PLDS_B
#undef PMFMA
#undef PTILE
#undef MFMA16
#undef VMBAR
#undef SCHED0

#pragma unroll
  for (int mt = 0; mt < 4; ++mt)
#pragma unroll
    for (int nt = 0; nt < 4; ++nt) {
      const int col = n0 + wn * 64 + nt * 16 + r16;
      const int rowbase = m0 + wm * 64 + mt * 16 + quad * 4;
#pragma unroll
      for (int r = 0; r < 4; ++r)
        C[(long)(rowbase + r) * N + col] = acc[mt][nt][r];
    }
}

// Flash attention v5: block = (b, h, 128 q) = 4 waves x 32 q.  64 keys per
// barrier via QUAD-buffered 32-key K/V tiles (stage 2 tiles, compute 2 halves
// per __syncthreads; 32 barriers/block vs 64).  LDS: Ks 4x8K + Vts 4x8K +
// Ps 4x2560 = 75008 B -> still 2 blocks/CU.  Inner half = verified v4 body.
// Q arrives pre-scaled by scale*log2e.
__global__ __launch_bounds__(256) void attn_kernel(const uint16_t* __restrict__ Q,
                                                   const uint16_t* __restrict__ K,
                                                   const uint16_t* __restrict__ Vt,
                                                   const float* __restrict__ bias,
                                                   uint16_t* __restrict__ O) {
  __shared__ __align__(16) uint16_t Ks[4][32 * 128];   // [key][chunk16 ^ (key&7)]
  __shared__ __align__(16) uint16_t Vts[4][128 * 32];  // [dim][keychunk ^ (dim&3)]
  __shared__ __align__(16) uint16_t Ps[4][32 * 40];    // per-wave P, stride 40 (pad)
  const int tid = threadIdx.x;
  const int lane = tid & 63;
  const int w = tid >> 6;
  const int r16 = lane & 15, quad = lane >> 4;
  const int h = blockIdx.y, b = blockIdx.z;
  const int qbase = blockIdx.x * 128 + w * 32;

  bf16x8 qf[2][4];
#pragma unroll
  for (int t = 0; t < 2; ++t) {
    const uint16_t* qb = Q + ((long)(b * 2048 + qbase + t * 16 + r16)) * 2048 + h * 128 + quad * 8;
#pragma unroll
    for (int c = 0; c < 4; ++c) qf[t][c] = *(const bf16x8*)(qb + c * 32);
  }
  f32x4 oacc[2][8] = {};
  float li[2][4] = {};

  uint16_t* PsW = &Ps[w][0];
  const float* brow = bias + b * 2048;

  const int key0[2] = {8 * w + quad, 8 * w + 4 + quad};
  const uint16_t* kg[2];
  const uint16_t* vg[2];
#pragma unroll
  for (int i = 0; i < 2; ++i) {
    kg[i] = K + ((long)(b * 2048 + key0[i])) * 2048 + h * 128 + 8 * (r16 ^ ((4 * i + quad) & 7));
    const int dim = 32 * w + 16 * i + (lane >> 2);
    vg[i] = Vt + ((long)((b * 16 + h) * 128 + dim)) * 2048 + 8 * ((lane & 3) ^ ((lane >> 2) & 3));
  }

  // prologue: stage tiles 0,1 into buffer pairs {0},{1}
#pragma unroll
  for (int tb = 0; tb < 2; ++tb)
#pragma unroll
    for (int i = 0; i < 2; ++i) {
      glds16(kg[i], &Ks[tb][(2 * w + i) * 512]);
      glds16(vg[i], &Vts[tb][(2 * w + i) * 512]);
      kg[i] += 32 * 2048;
      vg[i] += 32;
    }
  float bn0 = brow[r16], bn1 = brow[16 + r16];
  float bn2 = brow[32 + r16], bn3 = brow[48 + r16];

  // one 32-key half: QK^T -> exp -> P-write -> PV.  Verbatim v4 body.
  auto half_body = [&](const uint16_t* Kc, const uint16_t* Vc, float bv0, float bv1) {
#pragma unroll
    for (int ct = 0; ct < 2; ++ct) {
      const int key = ct * 16 + r16;
      const int kb = key & 7;
      bf16x8 kf[4];
#pragma unroll
      for (int c = 0; c < 4; ++c)
        kf[c] = *(const bf16x8*)(Kc + key * 128 + ((4 * c + quad) ^ kb) * 8);
      const float bv = ct ? bv1 : bv0;
      const int pc = ct * 2 + (r16 >> 3);
#pragma unroll
      for (int t = 0; t < 2; ++t) {
        f32x4 s = {};
#pragma unroll
        for (int c = 0; c < 4; ++c)
          s = __builtin_amdgcn_mfma_f32_16x16x32_bf16(qf[t][c], kf[c], s, 0, 0, 0);
#pragma unroll
        for (int r = 0; r < 4; ++r) {
          const float p = __builtin_amdgcn_exp2f(s[r] + bv);
          const uint32_t pb = f_as_u(p) + 0x8000u;  // round-half-up to bf16
          const int row = t * 16 + quad * 4 + r;    // row&3 == r
          PsW[row * 40 + ((pc ^ r) << 3) + (r16 & 7)] = (uint16_t)(pb >> 16);
          li[t][r] += u_as_f(pb & 0xffff0000u);
        }
      }
    }
    bf16x8 pa[2];
#pragma unroll
    for (int t = 0; t < 2; ++t)
      pa[t] = *(const bf16x8*)(PsW + (t * 16 + r16) * 40 + ((quad ^ (r16 & 3)) << 3));
#pragma unroll
    for (int nt = 0; nt < 8; ++nt) {
      const int dim = nt * 16 + r16;
      bf16x8 vf = *(const bf16x8*)(Vc + dim * 32 + ((quad ^ (dim & 3)) << 3));
#pragma unroll
      for (int t = 0; t < 2; ++t)
        oacc[t][nt] = __builtin_amdgcn_mfma_f32_16x16x32_bf16(pa[t], vf, oacc[t][nt], 0, 0, 0);
    }
  };

  // 64-key call: consume buffer pair {cur, cur+1}, stage into {cur^2, ...}
  auto body64 = [&](int j, int cur) {
    __syncthreads();
    const float bc0 = bn0, bc1 = bn1, bc2 = bn2, bc3 = bn3;
    if (j < 31) {
      const int nxt = cur ^ 2;
#pragma unroll
      for (int i = 0; i < 2; ++i) {
        glds16(kg[i], &Ks[nxt][(2 * w + i) * 512]);
        glds16(vg[i], &Vts[nxt][(2 * w + i) * 512]);
        kg[i] += 32 * 2048;
        vg[i] += 32;
        glds16(kg[i], &Ks[nxt + 1][(2 * w + i) * 512]);
        glds16(vg[i], &Vts[nxt + 1][(2 * w + i) * 512]);
        kg[i] += 32 * 2048;
        vg[i] += 32;
      }
      const int k0n = 64 * j + 64;
      bn0 = brow[k0n + r16];
      bn1 = brow[k0n + 16 + r16];
      bn2 = brow[k0n + 32 + r16];
      bn3 = brow[k0n + 48 + r16];
    }
    half_body(&Ks[cur][0], &Vts[cur][0], bc0, bc1);
    half_body(&Ks[cur + 1][0], &Vts[cur + 1][0], bc2, bc3);
  };

  for (int jj = 0; jj < 16; ++jj) {
    body64(2 * jj, 0);
    body64(2 * jj + 1, 2);
  }

#pragma unroll
  for (int off = 1; off < 16; off <<= 1)
#pragma unroll
    for (int t = 0; t < 2; ++t)
#pragma unroll
      for (int r = 0; r < 4; ++r) li[t][r] += __shfl_xor(li[t][r], off);

#pragma unroll
  for (int t = 0; t < 2; ++t) {
    uint16_t* ob = O + ((long)(b * 2048 + qbase + t * 16)) * 2048 + h * 128;
    float inv_l[4];
#pragma unroll
    for (int r = 0; r < 4; ++r) inv_l[r] = 1.0f / li[t][r];
#pragma unroll
    for (int nt = 0; nt < 8; ++nt)
#pragma unroll
      for (int r = 0; r < 4; ++r)
        ob[(long)(quad * 4 + r) * 2048 + nt * 16 + r16] = f2bf(oacc[t][nt][r] * inv_l[r]);
  }
}

extern "C" void kernel_launch(void* const* d_in, const int* in_sizes, int n_in,
                              void* d_out, int out_size, void* d_ws, size_t ws_size,
                              hipStream_t stream) {
  const float* x   = (const float*)d_in[0];
  const float* enc = (const float*)d_in[1];
  const int*   msk = (const int*)d_in[2];
  const float* Wq  = (const float*)d_in[3];
  const float* Wk  = (const float*)d_in[4];
  const float* Wv  = (const float*)d_in[5];
  const float* Wo  = (const float*)d_in[6];
  float* out = (float*)d_out;

  const long NELT = 8L * 1024 * 1024;  // 4096 x 2048 elems
  const long WELT = 4L * 1024 * 1024;  // 2048 x 2048 elems
  // d_ws (80 MiB + 16 KiB used): Qb[8M] Kb[8M] Vtb[8M] W4[16M] | bias
  uint16_t* Qb  = (uint16_t*)d_ws;
  uint16_t* Kb  = Qb + NELT;
  uint16_t* Vtb = Kb + NELT;
  uint16_t* W4  = Vtb + NELT;
  float* biasb  = (float*)(W4 + 4 * WELT);
  // d_out doubles as scratch for bf16 activations until the final GEMM overwrites it.
  uint16_t* xb   = (uint16_t*)d_out;        // 8M elems = 16 MB
  uint16_t* encb = xb + NELT;               // 8M elems = 16 MB (total 32 MB = out size)
  uint16_t* Ob   = W4;                      // Wq/Wk region dead after QKV GEMM

  const float cs_exp = 0.088388347648318447f * LOG2E;  // folded into Q

  convert_f32_bf16<<<(int)(NELT / 2048), 256, 0, stream>>>(x, xb);
  convert_f32_bf16<<<(int)(NELT / 2048), 256, 0, stream>>>(enc, encb);
  convert_w4<<<8192, 256, 0, stream>>>(Wq, Wk, Wv, Wo, W4);
  mask_bias<<<16, 256, 0, stream>>>(msk, biasb);

  // QKV mega-GEMM: 256^2 tiles, grid 16x24 = 384 blocks (384 % 8 == 0)
  gemm256<<<384, 512, 0, stream>>>(xb, encb, W4, Qb, Kb, Vtb,
                                   4096, 6144, 2048, cs_exp);

  attn_kernel<<<dim3(16, 16, 2), 256, 0, stream>>>(Qb, Kb, Vtb, biasb, Ob);

  // Final projection: 128x256 tiles, grid 32x8 = 256 blocks = one full round.
  gemm_proj<<<256, 512, 0, stream>>>(Ob, W4 + 3 * WELT, out, 4096, 2048, 2048);
}

// Round 6
// 445.259 us; speedup vs baseline: 1.0765x; 1.0765x over previous
//
#include <hip/hip_runtime.h>
#include <stdint.h>

// B=2, SQ=SK=2048, HIDDEN=2048, HEADS=16, HEAD_DIM=128.
// DTYPE MODEL (verified): inputs fp32, mask int32, OUTPUT fp32. Internal bf16 MFMA.
// Round 14: GEMMs unchanged (round-12 verified). Attention v6: 8 waves x 16 q
// (QBLK=128, grid 512 blocks), dual-buffered 32-key tiles, LDS 43008 B ->
// 2 blocks/CU x 8 waves = 16 waves/CU (4/SIMD, launch_bounds(512,4)).
// P-store layout made conflict-free: window = colw ^ ((row>>2)&3) -- the xor
// term varies WITHIN a store instr (row>>2 = quad), spreading 64 lanes over 8
// distinct 16B windows (old pc^r layout: 4 windows, 4 lanes/bank = measured
// 9.96e6 conflict cycles ~= 12% of attn time).

#define LOG2E 1.44269504088896340736f
#define INV2PI 0.15915494309189535f

typedef __attribute__((ext_vector_type(8))) short bf16x8;
typedef __attribute__((ext_vector_type(8))) uint16_t u16x8;
typedef __attribute__((ext_vector_type(4))) uint16_t u16x4;
typedef __attribute__((ext_vector_type(4))) float f32x4;

__device__ __forceinline__ uint16_t f2bf(float f) {
  union { float f; uint32_t i; } v; v.f = f;
  uint32_t x = v.i;
  return (uint16_t)((x + 0x7fffu + ((x >> 16) & 1u)) >> 16);  // RTN-even
}
__device__ __forceinline__ uint32_t f_as_u(float f) { union { float f; uint32_t u; } v; v.f = f; return v.u; }
__device__ __forceinline__ float u_as_f(uint32_t u) { union { uint32_t u; float f; } v; v.u = u; return v.f; }
__device__ __forceinline__ void glds16(const void* g, void* l) {
  __builtin_amdgcn_global_load_lds((const __attribute__((address_space(1))) void*)g,
                                   (__attribute__((address_space(3))) void*)l, 16, 0, 0);
}

// fp32 -> bf16, 8 elems/thread, exact grid (n % 2048 == 0).
__global__ __launch_bounds__(256) void convert_f32_bf16(const float* __restrict__ in,
                                                        uint16_t* __restrict__ out) {
  const long i = ((long)blockIdx.x * 256 + threadIdx.x) * 8;
  const f32x4 a = *(const f32x4*)(in + i);
  const f32x4 b = *(const f32x4*)(in + i + 4);
  u16x8 o;
#pragma unroll
  for (int j = 0; j < 4; ++j) { o[j] = f2bf(a[j]); o[4 + j] = f2bf(b[j]); }
  *(u16x8*)(out + i) = o;
}

// All four weights -> one contiguous bf16 buffer W4 = [Wq|Wk|Wv|Wo], 4M elems each.
__global__ __launch_bounds__(256) void convert_w4(const float* __restrict__ Wq,
                                                  const float* __restrict__ Wk,
                                                  const float* __restrict__ Wv,
                                                  const float* __restrict__ Wo,
                                                  uint16_t* __restrict__ W4) {
  const int blk = blockIdx.x;        // 8192 blocks, 2048 per section
  const int sec = blk >> 11;
  const long off = ((long)(blk & 2047) * 256 + threadIdx.x) * 8;
  const float* src = (sec == 0) ? Wq : (sec == 1) ? Wk : (sec == 2) ? Wv : Wo;
  const f32x4 a = *(const f32x4*)(src + off);
  const f32x4 b = *(const f32x4*)(src + off + 4);
  u16x8 o;
#pragma unroll
  for (int j = 0; j < 4; ++j) { o[j] = f2bf(a[j]); o[4 + j] = f2bf(b[j]); }
  *(u16x8*)(W4 + (long)sec * 4194304 + off) = o;
}

// mask int -> additive softmax bias float (0 or -inf). 4096 elems.
__global__ __launch_bounds__(256) void mask_bias(const int* __restrict__ m,
                                                 float* __restrict__ bias) {
  const int i = blockIdx.x * 256 + threadIdx.x;
  bias[i] = m[i] ? 0.0f : -__builtin_inff();
}

// c is the section-local column; C has row stride 2048.
__device__ __forceinline__ void epi_rope_store(uint16_t* C, const f32x4& a, int rowbase,
                                               int c, float oscale) {
  const int f = (c >> 1) & 63;
  const float inv = __builtin_amdgcn_exp2f((float)f * (-13.287712379549449f / 64.0f));
  const float sgn = (c & 1) ? 1.0f : -1.0f;
#pragma unroll
  for (int r = 0; r < 4; ++r) {
    const float val = a[r];
    const float partner = __shfl_xor(val, 1);
    const int s = (rowbase + r) & 2047;
    const float rev = __builtin_amdgcn_fractf((float)s * inv * INV2PI);
    const float sn = __builtin_amdgcn_sinf(rev);
    const float cs = __builtin_amdgcn_cosf(rev);
    C[(long)(rowbase + r) * 2048 + c] = f2bf((val * cs + sgn * partner * sn) * oscale);
  }
}

// ---------------------------------------------------------------------------
// QKV mega-GEMM: 256x256 tile, BK=64, 512 threads = 8 waves (2M x 4N).
// Round-10 verified structure: 2 counted-vmcnt syncs per K-tile.
// LDS map: [256 rows][4 slots of 8]; phys slot p at row r holds logical
// k-slot p ^ ((r>>1)&3); staged via pre-swizzled global source (rule 21).
// ---------------------------------------------------------------------------
__global__ __launch_bounds__(512, 2) void gemm256(const uint16_t* __restrict__ A0,
                                                  const uint16_t* __restrict__ A1,
                                                  const uint16_t* __restrict__ W,
                                                  uint16_t* __restrict__ Qb,
                                                  uint16_t* __restrict__ Kb,
                                                  uint16_t* __restrict__ Vtb,
                                                  int M, int N, int K, float oscale) {
  __shared__ __align__(16) uint16_t As[2][2][8192];  // [buf][kk][256*32] = 64 KiB
  __shared__ __align__(16) uint16_t Bs[2][2][8192];  // 64 KiB
  const int tid = threadIdx.x;
  const int lane = tid & 63;
  const int w = tid >> 6;
  const int r16 = lane & 15, quad = lane >> 4;
  const int wm = w >> 2, wn = w & 3;

  // bijective XCD swizzle (nwg % 8 == 0), column-chunked.
  const int nby = M >> 8;
  const int nwg = gridDim.x;
  const int wg = ((int)blockIdx.x & 7) * (nwg >> 3) + ((int)blockIdx.x >> 3);
  const int by = wg % nby, bx = wg / nby;
  const int m0 = by << 8, n0 = bx << 8;

  const uint16_t* A = (n0 >= 2048) ? A1 : A0;

  // staging: wave w owns chunks 2w, 2w+1 (16 rows each) of every half-tile
  const int srow = 2 * w * 16 + (lane >> 2);           // rows srow, srow+16
  const int ssl = (lane & 3) ^ ((srow >> 1) & 3);      // same for srow+16
  const uint16_t* Ag0 = A + (long)(m0 + srow) * K + ssl * 8;
  const uint16_t* Ag1 = Ag0 + (long)16 * K;
  const uint16_t* Bg0 = W + (long)(n0 + srow) * K + ssl * 8;
  const uint16_t* Bg1 = Bg0 + (long)16 * K;
  const int ldso = w << 10;  // element offset of this wave's first 1 KiB chunk

  // fragment read offsets (elements within one [buf][kk] plane)
  const int sw = (r16 >> 1) & 3;
  const int aoff = (wm * 128 + r16) * 32 + ((quad ^ sw) << 3);
  const int boff = (wn * 64 + r16) * 32 + ((quad ^ sw) << 3);

  f32x4 acc[8][4] = {};
  bf16x8 af[4], bfr[4];

#define SCHED0() __builtin_amdgcn_sched_barrier(0)
#define G_STAGE_A(BUF, KK, T) do { \
    glds16(Ag0 + (long)(T) * 64 + (KK) * 32, &As[BUF][KK][ldso]); \
    glds16(Ag1 + (long)(T) * 64 + (KK) * 32, &As[BUF][KK][ldso + 512]); } while (0)
#define G_STAGE_B(BUF, KK, T) do { \
    glds16(Bg0 + (long)(T) * 64 + (KK) * 32, &Bs[BUF][KK][ldso]); \
    glds16(Bg1 + (long)(T) * 64 + (KK) * 32, &Bs[BUF][KK][ldso + 512]); } while (0)
#define LDS_B(BUF, KK) do { _Pragma("unroll") \
    for (int i = 0; i < 4; ++i) bfr[i] = *(const bf16x8*)&Bs[BUF][KK][boff + i * 512]; } while (0)
#define LDS_A(BUF, KK, MH) do { _Pragma("unroll") \
    for (int i = 0; i < 4; ++i) af[i] = *(const bf16x8*)&As[BUF][KK][aoff + ((MH) * 4 + i) * 512]; } while (0)
#define MFMA16(MH) do { __builtin_amdgcn_s_setprio(1); _Pragma("unroll") \
    for (int mi = 0; mi < 4; ++mi) { _Pragma("unroll") \
      for (int nt = 0; nt < 4; ++nt) \
        acc[(MH) * 4 + mi][nt] = __builtin_amdgcn_mfma_f32_16x16x32_bf16(af[mi], bfr[nt], acc[(MH) * 4 + mi][nt], 0, 0, 0); } \
    __builtin_amdgcn_s_setprio(0); } while (0)
#define VMBAR(NN) do { SCHED0(); \
    asm volatile("s_waitcnt vmcnt(" #NN ")" ::: "memory"); \
    __builtin_amdgcn_s_barrier(); \
    SCHED0(); } while (0)
#define TILE_ITER(T, BC, BN) do { \
    G_STAGE_A(BN, 0, (T) + 1); LDS_B(BC, 0); LDS_A(BC, 0, 0); MFMA16(0); \
    G_STAGE_B(BN, 0, (T) + 1); LDS_A(BC, 0, 1); MFMA16(1); \
    VMBAR(4); \
    G_STAGE_A(BN, 1, (T) + 1); LDS_B(BC, 1); LDS_A(BC, 1, 0); MFMA16(0); \
    G_STAGE_B(BN, 1, (T) + 1); LDS_A(BC, 1, 1); MFMA16(1); \
    VMBAR(4); } while (0)

  // prologue: stage tile 0 fully; land k0 halves, keep k1 halves in flight
  G_STAGE_A(0, 0, 0); G_STAGE_B(0, 0, 0); G_STAGE_A(0, 1, 0); G_STAGE_B(0, 1, 0);
  VMBAR(4);

  const int NT = K >> 6;  // 32 (even); tiles 0..NT-1
  int t = 0;
  for (; t + 2 < NT; t += 2) { TILE_ITER(t, 0, 1); TILE_ITER(t + 1, 1, 0); }
  TILE_ITER(t, 0, 1);  // t == NT-2 (even): stages tile NT-1 into buf 1

  // peeled tail tile NT-1 (buf 1): no staging; drain its k1 at mid-tile
  LDS_B(1, 0); LDS_A(1, 0, 0); MFMA16(0);
  LDS_A(1, 0, 1); MFMA16(1);
  VMBAR(0);
  LDS_B(1, 1); LDS_A(1, 1, 0); MFMA16(0);
  LDS_A(1, 1, 1); MFMA16(1);

#undef G_STAGE_A
#undef G_STAGE_B
#undef LDS_A
#undef LDS_B
#undef TILE_ITER

#pragma unroll
  for (int mt = 0; mt < 8; ++mt)
#pragma unroll
    for (int nt = 0; nt < 4; ++nt) {
      const int col = n0 + wn * 64 + nt * 16 + r16;
      const int rowbase = m0 + wm * 128 + mt * 16 + quad * 4;
      if (n0 < 2048) {
        epi_rope_store(Qb, acc[mt][nt], rowbase, col, oscale);       // Q
      } else if (n0 < 4096) {
        epi_rope_store(Kb, acc[mt][nt], rowbase, col - 2048, 1.0f);  // K
      } else {
        const int c = col - 4096;
        const int h = c >> 7, d = c & 127;
        const int b = rowbase >> 11, s = rowbase & 2047;
        u16x4 pk;
#pragma unroll
        for (int r = 0; r < 4; ++r) pk[r] = f2bf(acc[mt][nt][r]);
        *(u16x4*)(Vtb + (long)((b * 16 + h) * 128 + d) * 2048 + s) = pk;
      }
    }
}

// ---------------------------------------------------------------------------
// Final projection: BM=128, BN=256, BK=64, 8 waves (2M x 4N) -> wave 64x64.
// Grid 32x8 = 256 blocks = one full round on 256 CUs.  vmcnt(3) ledger.
// LDS: As 2x2x[128x32]=32K + Bs 2x2x[256x32]=64K = 96 KiB.
// ---------------------------------------------------------------------------
__global__ __launch_bounds__(512, 2) void gemm_proj(const uint16_t* __restrict__ A0,
                                                    const uint16_t* __restrict__ W,
                                                    float* __restrict__ C,
                                                    int M, int N, int K) {
  __shared__ __align__(16) uint16_t As[2][2][4096];  // [buf][kk][128*32] = 32 KiB
  __shared__ __align__(16) uint16_t Bs[2][2][8192];  // [buf][kk][256*32] = 64 KiB
  const int tid = threadIdx.x;
  const int lane = tid & 63;
  const int w = tid >> 6;
  const int r16 = lane & 15, quad = lane >> 4;
  const int wm = w >> 2, wn = w & 3;

  const int nby = M >> 7;  // BM=128
  const int nwg = gridDim.x;
  const int wg = ((int)blockIdx.x & 7) * (nwg >> 3) + ((int)blockIdx.x >> 3);
  const int by = wg % nby, bx = wg / nby;
  const int m0 = by << 7, n0 = bx << 8;

  // staging: wave w owns A chunk w (16 rows) and B chunks 2w, 2w+1
  const int sa_row = 16 * w + (lane >> 2);
  const int sb_row = 32 * w + (lane >> 2);
  const int ssl = (lane & 3) ^ (((lane >> 2) >> 1) & 3);
  const uint16_t* Ag = A0 + (long)(m0 + sa_row) * K + ssl * 8;
  const uint16_t* Bg0 = W + (long)(n0 + sb_row) * K + ssl * 8;
  const uint16_t* Bg1 = Bg0 + (long)16 * K;

  const int sw = (r16 >> 1) & 3;
  const int aoff = (wm * 64 + r16) * 32 + ((quad ^ sw) << 3);
  const int boff = (wn * 64 + r16) * 32 + ((quad ^ sw) << 3);

  f32x4 acc[4][4] = {};
  bf16x8 af[4], bfr[4];

#define PG_STAGE_A(BUF, KK, T) \
    glds16(Ag + (long)(T) * 64 + (KK) * 32, &As[BUF][KK][w * 512])
#define PG_STAGE_B(BUF, KK, T) do { \
    glds16(Bg0 + (long)(T) * 64 + (KK) * 32, &Bs[BUF][KK][2 * w * 512]); \
    glds16(Bg1 + (long)(T) * 64 + (KK) * 32, &Bs[BUF][KK][2 * w * 512 + 512]); } while (0)
#define PLDS_B(BUF, KK) do { _Pragma("unroll") \
    for (int i = 0; i < 4; ++i) bfr[i] = *(const bf16x8*)&Bs[BUF][KK][boff + i * 512]; } while (0)
#define PLDS_A(BUF, KK) do { _Pragma("unroll") \
    for (int i = 0; i < 4; ++i) af[i] = *(const bf16x8*)&As[BUF][KK][aoff + i * 512]; } while (0)
#define PMFMA(MT0, MT1) do { __builtin_amdgcn_s_setprio(1); _Pragma("unroll") \
    for (int mi = (MT0); mi < (MT1); ++mi) { _Pragma("unroll") \
      for (int nt = 0; nt < 4; ++nt) \
        acc[mi][nt] = __builtin_amdgcn_mfma_f32_16x16x32_bf16(af[mi], bfr[nt], acc[mi][nt], 0, 0, 0); } \
    __builtin_amdgcn_s_setprio(0); } while (0)
#define PTILE(T, BC, BN) do { \
    PG_STAGE_A(BN, 0, (T) + 1); PLDS_B(BC, 0); PLDS_A(BC, 0); PMFMA(0, 2); \
    PG_STAGE_B(BN, 0, (T) + 1); PMFMA(2, 4); \
    VMBAR(3); \
    PG_STAGE_A(BN, 1, (T) + 1); PLDS_B(BC, 1); PLDS_A(BC, 1); PMFMA(0, 2); \
    PG_STAGE_B(BN, 1, (T) + 1); PMFMA(2, 4); \
    VMBAR(3); } while (0)

  PG_STAGE_A(0, 0, 0); PG_STAGE_B(0, 0, 0); PG_STAGE_A(0, 1, 0); PG_STAGE_B(0, 1, 0);
  VMBAR(3);

  const int NT = K >> 6;  // 32
  int t = 0;
  for (; t + 2 < NT; t += 2) { PTILE(t, 0, 1); PTILE(t + 1, 1, 0); }
  PTILE(t, 0, 1);

  PLDS_B(1, 0); PLDS_A(1, 0); PMFMA(0, 4);
  VMBAR(0);
  PLDS_B(1, 1); PLDS_A(1, 1); PMFMA(0, 4);

#undef PG_STAGE_A
#undef PG_STAGE_B
#undef PLDS_A
#undef PLDS_B
#undef PMFMA
#undef PTILE
#undef MFMA16
#undef VMBAR
#undef SCHED0

#pragma unroll
  for (int mt = 0; mt < 4; ++mt)
#pragma unroll
    for (int nt = 0; nt < 4; ++nt) {
      const int col = n0 + wn * 64 + nt * 16 + r16;
      const int rowbase = m0 + wm * 64 + mt * 16 + quad * 4;
#pragma unroll
      for (int r = 0; r < 4; ++r)
        C[(long)(rowbase + r) * N + col] = acc[mt][nt][r];
    }
}

// ---------------------------------------------------------------------------
// Flash attention v6: block = (b, h, 128 q) = 8 waves x 16 q each, 512 thr.
// Dual-buffered 32-key K/V tiles (1 barrier per tile), cross-barrier glds
// prefetch.  LDS: Ks 2x8K + Vts 2x8K + Ps 8x1280B = 43008 B -> 2 blocks/CU
// x 8 waves = 16 waves/CU (4/SIMD; launch_bounds(512,4) caps VGPR at 128).
// P layout (conflict-free): value P[row][col] (row=q 0..15, col=key 0..31)
// at u16 offset row*40 + (((col>>3) ^ (row>>2))<<3) + (col&7).  Writer lane
// (r16,quad) holds row=quad*4+r, col=ct*16+r16 -> window (pc^quad) varies
// with quad WITHIN the instr: 8 distinct 16B windows, 8 lanes each (exact
// 128B/cycle tiling).  Reader: row=r16, colw=quad -> window quad^(r16>>2),
// <=2-way (free).  Q arrives pre-scaled by scale*log2e.
// ---------------------------------------------------------------------------
__global__ __launch_bounds__(512, 4) void attn_kernel(const uint16_t* __restrict__ Q,
                                                      const uint16_t* __restrict__ K,
                                                      const uint16_t* __restrict__ Vt,
                                                      const float* __restrict__ bias,
                                                      uint16_t* __restrict__ O) {
  __shared__ __align__(16) uint16_t Ks[2][32 * 128];   // [key][chunk16 ^ (key&7)]
  __shared__ __align__(16) uint16_t Vts[2][128 * 32];  // [dim][keychunk ^ (dim&3)]
  __shared__ __align__(16) uint16_t Ps[8][16 * 40];    // per-wave P, conflict-free
  const int tid = threadIdx.x;
  const int lane = tid & 63;
  const int w = tid >> 6;                              // 8 waves
  const int r16 = lane & 15, quad = lane >> 4;
  const int h = blockIdx.y, b = blockIdx.z;
  const int qbase = blockIdx.x * 128 + w * 16;         // 16 q rows per wave

  // Q fragment: rows r16, k = c*32 + quad*8 + j
  bf16x8 qf[4];
  {
    const uint16_t* qb = Q + ((long)(b * 2048 + qbase + r16)) * 2048 + h * 128 + quad * 8;
#pragma unroll
    for (int c = 0; c < 4; ++c) qf[c] = *(const bf16x8*)(qb + c * 32);
  }
  f32x4 oacc[8] = {};
  float li[4] = {};

  uint16_t* PsW = &Ps[w][0];
  const float* brow = bias + b * 2048;

  // staging: wave w owns K chunk w (keys 4w..4w+3) and V chunk w (dims 16w..16w+15)
  const int kkey = 4 * w + quad;                        // key this lane stages
  const uint16_t* kg = K + ((long)(b * 2048 + kkey)) * 2048 + h * 128
                         + 8 * (r16 ^ (kkey & 7));
  const int vdim = 16 * w + (lane >> 2);
  const uint16_t* vg = Vt + ((long)((b * 16 + h) * 128 + vdim)) * 2048
                          + 8 * ((lane & 3) ^ ((lane >> 2) & 3));

  // prologue: stage tile 0 into buffer 0
  glds16(kg, &Ks[0][w * 512]);
  glds16(vg, &Vts[0][w * 512]);
  kg += 32 * 2048;
  vg += 32;
  float bn0 = brow[r16], bn1 = brow[16 + r16];

  auto body = [&](int k0, const uint16_t* Kc, const uint16_t* Vc,
                  uint16_t* Kn, uint16_t* Vn, bool pf) {
    __syncthreads();
    const float bc0 = bn0, bc1 = bn1;
    if (pf) {
      glds16(kg, Kn + w * 512);
      glds16(vg, Vn + w * 512);
      kg += 32 * 2048;
      vg += 32;
      bn0 = brow[k0 + 32 + r16];
      bn1 = brow[k0 + 48 + r16];
    }
    // QK^T -> exp -> P-store (conflict-free windows)
#pragma unroll
    for (int ct = 0; ct < 2; ++ct) {
      const int key = ct * 16 + r16;
      const int kb = key & 7;
      bf16x8 kf[4];
#pragma unroll
      for (int c = 0; c < 4; ++c)
        kf[c] = *(const bf16x8*)(Kc + key * 128 + ((4 * c + quad) ^ kb) * 8);
      const float bv = ct ? bc1 : bc0;
      const int pc = ct * 2 + (r16 >> 3);              // col>>3
      f32x4 s = {};
#pragma unroll
      for (int c = 0; c < 4; ++c)
        s = __builtin_amdgcn_mfma_f32_16x16x32_bf16(qf[c], kf[c], s, 0, 0, 0);
#pragma unroll
      for (int r = 0; r < 4; ++r) {
        const float p = __builtin_amdgcn_exp2f(s[r] + bv);
        const uint32_t pb = f_as_u(p) + 0x8000u;       // round-half-up to bf16
        const int row = quad * 4 + r;                  // q row (row>>2 == quad)
        PsW[row * 40 + ((pc ^ quad) << 3) + (r16 & 7)] = (uint16_t)(pb >> 16);
        li[r] += u_as_f(pb & 0xffff0000u);
      }
    }
    // PV: pa row = r16, logical col window = quad -> phys window quad^(r16>>2)
    bf16x8 pa = *(const bf16x8*)(PsW + r16 * 40 + ((quad ^ (r16 >> 2)) << 3));
#pragma unroll
    for (int nt = 0; nt < 8; ++nt) {
      const int dim = nt * 16 + r16;
      bf16x8 vf = *(const bf16x8*)(Vc + dim * 32 + ((quad ^ (dim & 3)) << 3));
      oacc[nt] = __builtin_amdgcn_mfma_f32_16x16x32_bf16(pa, vf, oacc[nt], 0, 0, 0);
    }
  };

  for (int kt2 = 0; kt2 < 32; ++kt2) {
    body(64 * kt2,      &Ks[0][0], &Vts[0][0], &Ks[1][0], &Vts[1][0], true);
    body(64 * kt2 + 32, &Ks[1][0], &Vts[1][0], &Ks[0][0], &Vts[0][0], kt2 < 31);
  }

  // li[r] partial over keys == r16 (mod 16); reduce across r16 only (off<16)
#pragma unroll
  for (int off = 1; off < 16; off <<= 1)
#pragma unroll
    for (int r = 0; r < 4; ++r) li[r] += __shfl_xor(li[r], off);

  uint16_t* ob = O + ((long)(b * 2048 + qbase)) * 2048 + h * 128;
  float inv_l[4];
#pragma unroll
  for (int r = 0; r < 4; ++r) inv_l[r] = 1.0f / li[r];
#pragma unroll
  for (int nt = 0; nt < 8; ++nt)
#pragma unroll
    for (int r = 0; r < 4; ++r)
      ob[(long)(quad * 4 + r) * 2048 + nt * 16 + r16] = f2bf(oacc[nt][r] * inv_l[r]);
}

extern "C" void kernel_launch(void* const* d_in, const int* in_sizes, int n_in,
                              void* d_out, int out_size, void* d_ws, size_t ws_size,
                              hipStream_t stream) {
  const float* x   = (const float*)d_in[0];
  const float* enc = (const float*)d_in[1];
  const int*   msk = (const int*)d_in[2];
  const float* Wq  = (const float*)d_in[3];
  const float* Wk  = (const float*)d_in[4];
  const float* Wv  = (const float*)d_in[5];
  const float* Wo  = (const float*)d_in[6];
  float* out = (float*)d_out;

  const long NELT = 8L * 1024 * 1024;  // 4096 x 2048 elems
  const long WELT = 4L * 1024 * 1024;  // 2048 x 2048 elems
  // d_ws (80 MiB + 16 KiB used): Qb[8M] Kb[8M] Vtb[8M] W4[16M] | bias
  uint16_t* Qb  = (uint16_t*)d_ws;
  uint16_t* Kb  = Qb + NELT;
  uint16_t* Vtb = Kb + NELT;
  uint16_t* W4  = Vtb + NELT;
  float* biasb  = (float*)(W4 + 4 * WELT);
  // d_out doubles as scratch for bf16 activations until the final GEMM overwrites it.
  uint16_t* xb   = (uint16_t*)d_out;        // 8M elems = 16 MB
  uint16_t* encb = xb + NELT;               // 8M elems = 16 MB (total 32 MB = out size)
  uint16_t* Ob   = W4;                      // Wq/Wk region dead after QKV GEMM

  const float cs_exp = 0.088388347648318447f * LOG2E;  // folded into Q

  convert_f32_bf16<<<(int)(NELT / 2048), 256, 0, stream>>>(x, xb);
  convert_f32_bf16<<<(int)(NELT / 2048), 256, 0, stream>>>(enc, encb);
  convert_w4<<<8192, 256, 0, stream>>>(Wq, Wk, Wv, Wo, W4);
  mask_bias<<<16, 256, 0, stream>>>(msk, biasb);

  // QKV mega-GEMM: 256^2 tiles, grid 16x24 = 384 blocks (384 % 8 == 0)
  gemm256<<<384, 512, 0, stream>>>(xb, encb, W4, Qb, Kb, Vtb,
                                   4096, 6144, 2048, cs_exp);

  attn_kernel<<<dim3(16, 16, 2), 512, 0, stream>>>(Qb, Kb, Vtb, biasb, Ob);

  // Final projection: 128x256 tiles, grid 32x8 = 256 blocks = one full round.
  gemm_proj<<<256, 512, 0, stream>>>(Ob, W4 + 3 * WELT, out, 4096, 2048, 2048);
}